// Round 13
// baseline (72.218 us; speedup 1.0000x reference)
//
#include <hip/hip_runtime.h>
#include <hip/hip_bf16.h>

typedef unsigned short u16;
typedef __bf16 bf16x8 __attribute__((ext_vector_type(8)));
typedef float f32x4 __attribute__((ext_vector_type(4)));
typedef float f32x16 __attribute__((ext_vector_type(16)));
typedef unsigned short ushort8 __attribute__((ext_vector_type(8)));

#define C_IN   128
#define C_OUT  256
#define BATCH  16
#define LEN    4096
#define KS     9
#define PAD    4
#define LPAD   (LEN + 2*PAD)      // 4104
#define KTOT   (C_IN * KS)        // 1152
#define NSTEP  72                 // K = 1152 / 16

#define XT_BLKS    1040           // 65 * 16
#define W5_BLKS    1152           // 294912 / 256
#define EB_BLKS    256

__device__ inline u16 f2bf(float f) {
    __hip_bfloat16 h = __float2bfloat16(f);
    return __builtin_bit_cast(u16, h);
}

// async global->LDS, 16B per lane, wave-uniform LDS base + lane*16
__device__ __forceinline__ void g2l16(const void* g, void* l) {
    __builtin_amdgcn_global_load_lds(
        (const __attribute__((address_space(1))) void*)g,
        (__attribute__((address_space(3))) void*)l, 16, 0, 0);
}

// ---------------------------------------------------------------------------
// Fused prep (one launch) — UNCHANGED (verified absmax 0.03125 since R9):
//  blocks [0,1040): x [B][C][L] f32 -> xt [B][LPAD][C] bf16, edge-padded,
//    4-bit XOR swizzle (16B-block idx ^= l&15) baked into global layout.
//  blocks [1040,2192): weight -> w5 in 32-lane fragment order for
//    mfma_f32_32x32x16_bf16:  i = ((s*8 + g)*64 + lane)*8 + e  where
//    o = g*32 + (lane&31), hi = lane>>5, c = (s&7)*16 + hi*8 + e, k = s>>3.
//  blocks [2192,2448): ebias[o] = bias[o] + sum offset*W; block 2192: phys.
// ---------------------------------------------------------------------------
__global__ void prep_all(const float* __restrict__ x, const float* __restrict__ w,
                         const float* __restrict__ bias, const float* __restrict__ vel,
                         const float* __restrict__ acc_in,
                         u16* __restrict__ xt, u16* __restrict__ w5,
                         float* __restrict__ ebias, float* __restrict__ phys_out) {
    int bid = blockIdx.x;
    int t = threadIdx.x;
    if (bid < XT_BLKS) {
        int b    = bid / 65;
        int lblk = bid % 65;
        int lane = t & 63;
        int jb   = t >> 6;
        int lp   = lblk * 64 + lane;
        if (lp >= LPAD) return;
        int l = lp - PAD;
        l = l < 0 ? 0 : (l > LEN - 1 ? LEN - 1 : l);
        const float* xb = x + (size_t)b * C_IN * LEN + l;
        u16* row = xt + ((size_t)b * LPAD + lp) * C_IN;
        int key = lp & 15;
        #pragma unroll
        for (int jj = 0; jj < 4; ++jj) {
            int cblk = jb * 4 + jj;
            ushort8 v;
            #pragma unroll
            for (int e = 0; e < 8; ++e)
                v[e] = f2bf(xb[(size_t)(cblk * 8 + e) * LEN]);
            int jstore = cblk ^ key;
            *reinterpret_cast<ushort8*>(row + jstore * 8) = v;
        }
        return;
    }
    if (bid < XT_BLKS + W5_BLKS) {
        int i = (bid - XT_BLKS) * 256 + t;   // 294912 total
        int e    = i & 7;
        int lane = (i >> 3) & 63;
        int g    = (i >> 9) & 7;
        int s    = i >> 12;                  // 0..71
        int o    = g * 32 + (lane & 31);
        int hi   = lane >> 5;
        int c    = (s & 7) * 16 + hi * 8 + e;
        int k    = s >> 3;
        w5[i] = f2bf(w[((size_t)o * C_IN + c) * KS + k]);
        return;
    }
    __shared__ float red[256];
    int o = bid - (XT_BLKS + W5_BLKS);
    float sum = 0.f;
    for (int i = t; i < KTOT; i += 256) {
        int k = i % KS;                    // offset layout [c][k]
        float tk = k * 0.01f;              // DT
        float off = vel[i] * tk + 0.5f * acc_in[i] * tk * tk;
        sum += off * w[(size_t)o * KTOT + i];
    }
    red[t] = sum;
    __syncthreads();
    for (int h = 128; h > 0; h >>= 1) {
        if (t < h) red[t] += red[t + h];
        __syncthreads();
    }
    if (t == 0) ebias[o] = bias[o] + red[0];

    if (o == 0) {                          // phys
        __syncthreads();
        float pv = 0.f;
        for (int i = t; i < KTOT; i += 256) {
            float v = vel[i], a = acc_in[i];
            pv += v * v + a * a;
        }
        red[t] = pv;
        __syncthreads();
        for (int h = 128; h > 0; h >>= 1) {
            if (t < h) red[t] += red[t + h];
            __syncthreads();
        }
        if (t == 0) *phys_out = 0.01f * (red[0] / (float)KTOT);
    }
}

// ---------------------------------------------------------------------------
// Main: TLP fix. R11/R12 ran exactly 1 wave/SIMD (1024 waves on 1024 SIMDs)
// -> MfmaUtil 34% = pure MFMA work (15.4us) over total time; the other 65%
// was unfilled dependency latency. This round: wave tile 64o x 128l
// (acc 128 AGPR + ~100 VGPR ~ 230 unified < 256) -> 2 waves/SIMD.
// Block = 4 waves (wm 0..3) = 256o x 128l; grid 512 x 4 = 2048 waves = 2/SIMD.
// Per-CU budgets: MFMA 15.4us, B-LDS 2.3MB ~ 11us, A-L2 1.15MB ~ 8.6us
// -> MFMA-bound, with partner-wave MFMA filling each wave's load latency.
//  - B (x-tile, 34816B) staged ONCE via g2l16; the only barrier.
//  - A global->reg from L2-resident w5 (2 contiguous 1KB frags/step/wave,
//    wm-disjoint), register dbuf at distance 1.
//  - B ds_read dbuf at distance 1; no mid-loop barriers or waitcnt asm.
// ---------------------------------------------------------------------------
__global__ __launch_bounds__(256, 2) void conv_main(const u16* __restrict__ xt,
                                                    const u16* __restrict__ w5,
                                                    const float* __restrict__ ebias,
                                                    float* __restrict__ out) {
    __shared__ u16 ldsx[17408];            // B tile: 136 rows x 256B = 34816 B

    int b     = blockIdx.y;
    int lbase = blockIdx.x * 128;
    int t     = threadIdx.x;               // 0..255
    int lane  = t & 63;
    int wm    = t >> 6;                    // wave = o-quarter (64 o each)
    int l31   = lane & 31;
    int hi    = lane >> 5;

    // A source: wave wm's 2 o-groups (g = wm*2+mi) -> contiguous 2KB/step
    const u16* alane = w5 + ((size_t)(wm * 2) * 64 + lane) * 8;

    #define LOAD_A(S, AF)                                                        \
        {                                                                        \
            const u16* p_ = alane + (size_t)(S) * 4096;                          \
            _Pragma("unroll")                                                    \
            for (int mi = 0; mi < 2; ++mi)                                       \
                AF[mi] = *reinterpret_cast<const bf16x8*>(p_ + mi * 512);        \
        }
    #define LOAD_B(S, BF)                                                        \
        {                                                                        \
            int k_ = (S) >> 3;                                                   \
            int sl_ = ((S) & 7) * 2 + hi;                                        \
            _Pragma("unroll")                                                    \
            for (int nj = 0; nj < 4; ++nj) {                                     \
                int row_  = nj * 32 + l31 + k_;                                  \
                int addr_ = row_ * 256 + ((sl_ ^ (row_ & 15)) << 4);             \
                BF[nj] = *reinterpret_cast<const bf16x8*>(ldsbase + addr_);      \
            }                                                                    \
        }
    #define MFMA8(AF, BF)                                                        \
        {                                                                        \
            _Pragma("unroll")                                                    \
            for (int mi = 0; mi < 2; ++mi)                                       \
                _Pragma("unroll")                                                \
                for (int nj = 0; nj < 4; ++nj)                                   \
                    acc[mi][nj] = __builtin_amdgcn_mfma_f32_32x32x16_bf16(       \
                        AF[mi], BF[nj], acc[mi][nj], 0, 0, 0);                   \
        }

    bf16x8 aA[2], aB[2], bA[4], bB[4];

    // ---- prologue: stage B tile (2176 16B-units; 8 full calls + half call)
    {
        const u16* bsrc = xt + ((size_t)b * LPAD + lbase) * C_IN;
        #pragma unroll
        for (int j = 0; j < 8; ++j)
            g2l16(bsrc + (j * 256 + t) * 8, ldsx + (j * 256 + wm * 64) * 8);
        if (t < 128)
            g2l16(bsrc + (2048 + t) * 8, ldsx + (2048 + wm * 64) * 8);
    }
    LOAD_A(0, aA);                         // independent of LDS; issue early
    __syncthreads();                       // drains staging; the only barrier

    f32x16 acc[2][4] = {};
    const char* ldsbase = reinterpret_cast<const char*>(ldsx);
    LOAD_B(0, bA);

    #pragma unroll
    for (int s = 0; s < NSTEP; s += 2) {
        LOAD_A(s + 1, aB);
        LOAD_B(s + 1, bB);
        MFMA8(aA, bA);
        if (s + 2 < NSTEP) { LOAD_A(s + 2, aA); LOAD_B(s + 2, bA); }
        MFMA8(aB, bB);
    }

    // ---- epilogue: 32x32 D layout col = lane&31 (l), row = (reg&3)+8*(reg>>2)+4*hi
    #pragma unroll
    for (int mi = 0; mi < 2; ++mi) {
        int o0 = wm * 64 + mi * 32 + hi * 4;
        #pragma unroll
        for (int nj = 0; nj < 4; ++nj) {
            int l = lbase + nj * 32 + l31;
            #pragma unroll
            for (int q = 0; q < 4; ++q) {
                f32x4 eb = *reinterpret_cast<const f32x4*>(ebias + o0 + q * 8);
                float* op = out + (size_t)(b * C_OUT + o0 + q * 8) * LEN + l;
                #pragma unroll
                for (int p = 0; p < 4; ++p)
                    op[(size_t)p * LEN] = acc[mi][nj][q * 4 + p] + eb[p];
            }
        }
    }
    #undef LOAD_A
    #undef LOAD_B
    #undef MFMA8
}

extern "C" void kernel_launch(void* const* d_in, const int* in_sizes, int n_in,
                              void* d_out, int out_size, void* d_ws, size_t ws_size,
                              hipStream_t stream) {
    const float* x      = (const float*)d_in[0];
    const float* weight = (const float*)d_in[1];
    const float* bias   = (const float*)d_in[2];
    const float* vel    = (const float*)d_in[3];
    const float* acc    = (const float*)d_in[4];
    float* out = (float*)d_out;

    char* ws = (char*)d_ws;
    u16*  xt    = (u16*)ws;                                       // 16,797,696 B
    u16*  w5    = (u16*)(ws + (size_t)BATCH * LPAD * C_IN * 2);   // 589,824 B
    float* ebias = (float*)(ws + (size_t)BATCH * LPAD * C_IN * 2 + (size_t)C_OUT * KTOT * 2);

    hipLaunchKernelGGL(prep_all, dim3(XT_BLKS + W5_BLKS + EB_BLKS), dim3(256), 0, stream,
                       x, weight, bias, vel, acc, xt, w5, ebias,
                       out + (size_t)BATCH * C_OUT * LEN);
    hipLaunchKernelGGL(conv_main, dim3(LEN / 128, BATCH), dim3(256), 0, stream,
                       xt, w5, ebias, out);
}

// Round 14
// 60.247 us; speedup vs baseline: 1.1987x; 1.1987x over previous
//
#include <hip/hip_runtime.h>
#include <hip/hip_bf16.h>

typedef unsigned short u16;
typedef __bf16 bf16x8 __attribute__((ext_vector_type(8)));
typedef float f32x4 __attribute__((ext_vector_type(4)));
typedef float f32x16 __attribute__((ext_vector_type(16)));
typedef unsigned short ushort8 __attribute__((ext_vector_type(8)));

#define C_IN   128
#define C_OUT  256
#define BATCH  16
#define LEN    4096
#define KS     9
#define PAD    4
#define LPAD   (LEN + 2*PAD)      // 4104
#define KTOT   (C_IN * KS)        // 1152
#define NSTEP  72                 // K = 1152 / 16

#define XT_BLKS    1040           // 65 * 16
#define W5_BLKS    1152           // 294912 / 256
#define EB_BLKS    256

__device__ inline u16 f2bf(float f) {
    __hip_bfloat16 h = __float2bfloat16(f);
    return __builtin_bit_cast(u16, h);
}

// async global->LDS, 16B per lane, wave-uniform LDS base + lane*16
__device__ __forceinline__ void g2l16(const void* g, void* l) {
    __builtin_amdgcn_global_load_lds(
        (const __attribute__((address_space(1))) void*)g,
        (__attribute__((address_space(3))) void*)l, 16, 0, 0);
}

// ---------------------------------------------------------------------------
// Fused prep (one launch) — UNCHANGED (verified absmax 0.03125 since R9):
//  blocks [0,1040): x [B][C][L] f32 -> xt [B][LPAD][C] bf16, edge-padded,
//    4-bit XOR swizzle (16B-block idx ^= l&15) baked into global layout.
//  blocks [1040,2192): weight -> w5 in 32-lane fragment order for
//    mfma_f32_32x32x16_bf16:  i = ((s*8 + g)*64 + lane)*8 + e  where
//    o = g*32 + (lane&31), hi = lane>>5, c = (s&7)*16 + hi*8 + e, k = s>>3.
//  blocks [2192,2448): ebias[o] = bias[o] + sum offset*W; block 2192: phys.
// ---------------------------------------------------------------------------
__global__ void prep_all(const float* __restrict__ x, const float* __restrict__ w,
                         const float* __restrict__ bias, const float* __restrict__ vel,
                         const float* __restrict__ acc_in,
                         u16* __restrict__ xt, u16* __restrict__ w5,
                         float* __restrict__ ebias, float* __restrict__ phys_out) {
    int bid = blockIdx.x;
    int t = threadIdx.x;
    if (bid < XT_BLKS) {
        int b    = bid / 65;
        int lblk = bid % 65;
        int lane = t & 63;
        int jb   = t >> 6;
        int lp   = lblk * 64 + lane;
        if (lp >= LPAD) return;
        int l = lp - PAD;
        l = l < 0 ? 0 : (l > LEN - 1 ? LEN - 1 : l);
        const float* xb = x + (size_t)b * C_IN * LEN + l;
        u16* row = xt + ((size_t)b * LPAD + lp) * C_IN;
        int key = lp & 15;
        #pragma unroll
        for (int jj = 0; jj < 4; ++jj) {
            int cblk = jb * 4 + jj;
            ushort8 v;
            #pragma unroll
            for (int e = 0; e < 8; ++e)
                v[e] = f2bf(xb[(size_t)(cblk * 8 + e) * LEN]);
            int jstore = cblk ^ key;
            *reinterpret_cast<ushort8*>(row + jstore * 8) = v;
        }
        return;
    }
    if (bid < XT_BLKS + W5_BLKS) {
        int i = (bid - XT_BLKS) * 256 + t;   // 294912 total
        int e    = i & 7;
        int lane = (i >> 3) & 63;
        int g    = (i >> 9) & 7;
        int s    = i >> 12;                  // 0..71
        int o    = g * 32 + (lane & 31);
        int hi   = lane >> 5;
        int c    = (s & 7) * 16 + hi * 8 + e;
        int k    = s >> 3;
        w5[i] = f2bf(w[((size_t)o * C_IN + c) * KS + k]);
        return;
    }
    __shared__ float red[256];
    int o = bid - (XT_BLKS + W5_BLKS);
    float sum = 0.f;
    for (int i = t; i < KTOT; i += 256) {
        int k = i % KS;                    // offset layout [c][k]
        float tk = k * 0.01f;              // DT
        float off = vel[i] * tk + 0.5f * acc_in[i] * tk * tk;
        sum += off * w[(size_t)o * KTOT + i];
    }
    red[t] = sum;
    __syncthreads();
    for (int h = 128; h > 0; h >>= 1) {
        if (t < h) red[t] += red[t + h];
        __syncthreads();
    }
    if (t == 0) ebias[o] = bias[o] + red[0];

    if (o == 0) {                          // phys
        __syncthreads();
        float pv = 0.f;
        for (int i = t; i < KTOT; i += 256) {
            float v = vel[i], a = acc_in[i];
            pv += v * v + a * a;
        }
        red[t] = pv;
        __syncthreads();
        for (int h = 128; h > 0; h >>= 1) {
            if (t < h) red[t] += red[t + h];
            __syncthreads();
        }
        if (t == 0) *phys_out = 0.01f * (red[0] / (float)KTOT);
    }
}

// ---------------------------------------------------------------------------
// Main: R11 fat-wave base (41.7us, best) with ONE change: A-loads go through
// WAVE-PRIVATE LDS rings instead of global->reg at distance 1.
// Why: per-step accounting showed 512cyc MFMA + ~880cyc stall at 1 wave/SIMD;
// 880cyc = L3-class latency (FETCH 11MB << logical 300MB of w5 re-reads =>
// A served by L2/L3; L3 latency > the 540cyc distance-1 cover).
// Fix: ring of 4 x 4KB per wave (wm-disjoint => ZERO barriers, per-wave
// counted vmcnt only). Per step: STAGE_A(s+3) (4x g2l16), vmcnt(8) (leaves
// stage s+2,s+3 in flight - never drains), lane-linear conflict-free
// ds_read_b128 A-frags (~120cyc, covered by the 512cyc MFMA cluster).
// Global latency is buried 3 steps (~1600cyc) deep.
// Race audit: ring slot (S&3) is rewritten by STAGE_A(S) at step S-3; its
// previous reads (A(S-4) regs) were ds_reads issued at step S-5 and
// lgkm-completed before MFMA at step S-4 < stage issue at S-3 => no WAR.
// No cross-wave sharing (rings wave-private; B is read-only after prologue).
// LDS = 34816 (B) + 32768 (rings) = 67584 B -> 2 blocks/CU.
// ---------------------------------------------------------------------------
__global__ __launch_bounds__(128, 1) void conv_main(const u16* __restrict__ xt,
                                                    const u16* __restrict__ w5,
                                                    const float* __restrict__ ebias,
                                                    float* __restrict__ out) {
    __shared__ u16 ldsx[17408];            // B tile: 136 rows x 256B = 34816 B
    __shared__ u16 ldsa[2 * 4 * 2048];     // A rings: 2 waves x 4 slots x 4KB

    int b     = blockIdx.y;
    int lbase = blockIdx.x * 128;
    int t     = threadIdx.x;               // 0..127
    int lane  = t & 63;
    int wm    = t >> 6;                    // wave = o-half (128 o each)
    int l31   = lane & 31;
    int hi    = lane >> 5;

    // A source: wave wm's 4 o-groups (g = wm*4+mi) -> contiguous 4KB/step
    const u16* alane = w5 + ((size_t)(wm * 4) * 64 + lane) * 8;
    u16* aring = ldsa + wm * 8192;         // this wave's 4-slot ring

    #define STAGE_A(S)                                                           \
        {                                                                        \
            const u16* p_ = alane + (size_t)(S) * 4096;                          \
            u16* d_ = aring + ((S) & 3) * 2048;                                  \
            _Pragma("unroll")                                                    \
            for (int mi = 0; mi < 4; ++mi)                                       \
                g2l16(p_ + mi * 512, d_ + mi * 512);                             \
        }
    #define LOAD_A(BUF, AF)                                                      \
        {                                                                        \
            const u16* ab_ = aring + (BUF) * 2048 + lane * 8;                    \
            _Pragma("unroll")                                                    \
            for (int mi = 0; mi < 4; ++mi)                                       \
                AF[mi] = *reinterpret_cast<const bf16x8*>(ab_ + mi * 512);       \
        }
    #define LOAD_B(S, BF)                                                        \
        {                                                                        \
            int k_ = (S) >> 3;                                                   \
            int sl_ = ((S) & 7) * 2 + hi;                                        \
            _Pragma("unroll")                                                    \
            for (int nj = 0; nj < 4; ++nj) {                                     \
                int row_  = nj * 32 + l31 + k_;                                  \
                int addr_ = row_ * 256 + ((sl_ ^ (row_ & 15)) << 4);             \
                BF[nj] = *reinterpret_cast<const bf16x8*>(ldsbase + addr_);      \
            }                                                                    \
        }
    #define MFMA16(AF, BF)                                                       \
        {                                                                        \
            _Pragma("unroll")                                                    \
            for (int mi = 0; mi < 4; ++mi)                                       \
                _Pragma("unroll")                                                \
                for (int nj = 0; nj < 4; ++nj)                                   \
                    acc[mi][nj] = __builtin_amdgcn_mfma_f32_32x32x16_bf16(       \
                        AF[mi], BF[nj], acc[mi][nj], 0, 0, 0);                   \
        }
    // After STAGE_A(S+3): outstanding = stages S+1,S+2,S+3 (4 calls each).
    // vmcnt(8) retires the oldest 4 => stage(S+1) landed before LOAD_A(S+1).
    // Tail steps have fewer in flight -> exact smaller constants.
    #define WAITV(S)                                                             \
        {                                                                        \
            if ((S) + 3 < NSTEP)                                                 \
                asm volatile("s_waitcnt vmcnt(8)" ::: "memory");                 \
            else if ((S) + 2 < NSTEP)                                            \
                asm volatile("s_waitcnt vmcnt(4)" ::: "memory");                 \
            else if ((S) + 1 < NSTEP)                                            \
                asm volatile("s_waitcnt vmcnt(0)" ::: "memory");                 \
        }

    bf16x8 aA[4], aB[4], bA[4], bB[4];

    // ---- prologue: stage B tile (17 calls) + ring-fill A(0..2)
    {
        const u16* bsrc = xt + ((size_t)b * LPAD + lbase) * C_IN;
        #pragma unroll
        for (int j = 0; j < 17; ++j)
            g2l16(bsrc + (j * 128 + t) * 8, ldsx + (j * 128 + wm * 64) * 8);
        STAGE_A(0); STAGE_A(1); STAGE_A(2);
    }
    __syncthreads();                       // drains all staging; the only barrier

    f32x16 acc[4][4] = {};
    const char* ldsbase = reinterpret_cast<const char*>(ldsx);
    LOAD_A(0, aA);
    LOAD_B(0, bA);

    #pragma unroll
    for (int s = 0; s < NSTEP; s += 2) {
        // ---- even step s (regs A) ----
        if (s + 3 < NSTEP) STAGE_A(s + 3);
        WAITV(s);
        LOAD_A((s + 1) & 3, aB);
        LOAD_B(s + 1, bB);
        MFMA16(aA, bA);
        // ---- odd step s+1 (regs B) ----
        if (s + 4 < NSTEP) STAGE_A(s + 4);
        if (s + 2 < NSTEP) {
            WAITV(s + 1);
            LOAD_A((s + 2) & 3, aA);
            LOAD_B(s + 2, bA);
        }
        MFMA16(aB, bB);
    }

    // ---- epilogue: 32x32 D layout col = lane&31 (l), row = (reg&3)+8*(reg>>2)+4*hi
    #pragma unroll
    for (int mi = 0; mi < 4; ++mi) {
        int o0 = wm * 128 + mi * 32 + hi * 4;
        #pragma unroll
        for (int nj = 0; nj < 4; ++nj) {
            int l = lbase + nj * 32 + l31;
            #pragma unroll
            for (int q = 0; q < 4; ++q) {
                f32x4 eb = *reinterpret_cast<const f32x4*>(ebias + o0 + q * 8);
                float* op = out + (size_t)(b * C_OUT + o0 + q * 8) * LEN + l;
                #pragma unroll
                for (int p = 0; p < 4; ++p)
                    op[(size_t)p * LEN] = acc[mi][nj][q * 4 + p] + eb[p];
            }
        }
    }
    #undef STAGE_A
    #undef LOAD_A
    #undef LOAD_B
    #undef MFMA16
    #undef WAITV
}

extern "C" void kernel_launch(void* const* d_in, const int* in_sizes, int n_in,
                              void* d_out, int out_size, void* d_ws, size_t ws_size,
                              hipStream_t stream) {
    const float* x      = (const float*)d_in[0];
    const float* weight = (const float*)d_in[1];
    const float* bias   = (const float*)d_in[2];
    const float* vel    = (const float*)d_in[3];
    const float* acc    = (const float*)d_in[4];
    float* out = (float*)d_out;

    char* ws = (char*)d_ws;
    u16*  xt    = (u16*)ws;                                       // 16,797,696 B
    u16*  w5    = (u16*)(ws + (size_t)BATCH * LPAD * C_IN * 2);   // 589,824 B
    float* ebias = (float*)(ws + (size_t)BATCH * LPAD * C_IN * 2 + (size_t)C_OUT * KTOT * 2);

    hipLaunchKernelGGL(prep_all, dim3(XT_BLKS + W5_BLKS + EB_BLKS), dim3(256), 0, stream,
                       x, weight, bias, vel, acc, xt, w5, ebias,
                       out + (size_t)BATCH * C_OUT * LEN);
    hipLaunchKernelGGL(conv_main, dim3(LEN / 128, BATCH), dim3(128), 0, stream,
                       xt, w5, ebias, out);
}

// Round 15
// 51.792 us; speedup vs baseline: 1.3944x; 1.1632x over previous
//
#include <hip/hip_runtime.h>
#include <hip/hip_bf16.h>

typedef unsigned short u16;
typedef __bf16 bf16x8 __attribute__((ext_vector_type(8)));
typedef float f32x4 __attribute__((ext_vector_type(4)));
typedef float f32x16 __attribute__((ext_vector_type(16)));
typedef unsigned short ushort8 __attribute__((ext_vector_type(8)));

#define C_IN   128
#define C_OUT  256
#define BATCH  16
#define LEN    4096
#define KS     9
#define PAD    4
#define KTOT   (C_IN * KS)        // 1152
#define NSTEP  72                 // K = 1152 / 16

#define W5_BLKS    1152           // 294912 / 256
#define EB_BLKS    256

__device__ inline u16 f2bf(float f) {
    __hip_bfloat16 h = __float2bfloat16(f);
    return __builtin_bit_cast(u16, h);
}

// async global->LDS, 16B per lane, wave-uniform LDS base + lane*16
__device__ __forceinline__ void g2l16(const void* g, void* l) {
    __builtin_amdgcn_global_load_lds(
        (const __attribute__((address_space(1))) void*)g,
        (__attribute__((address_space(3))) void*)l, 16, 0, 0);
}

// ---------------------------------------------------------------------------
// Prep (small, one launch — prep_xt is now FUSED into conv_main):
//  blocks [0,1152): weight -> w5 in 32-lane fragment order for
//    mfma_f32_32x32x16_bf16:  i = ((s*8 + g)*64 + lane)*8 + e  where
//    o = g*32 + (lane&31), hi = lane>>5, c = (s&7)*16 + hi*8 + e, k = s>>3.
//  blocks [1152,1408): ebias[o] = bias[o] + sum offset*W; block 1152: phys.
// ---------------------------------------------------------------------------
__global__ void prep_all(const float* __restrict__ w,
                         const float* __restrict__ bias, const float* __restrict__ vel,
                         const float* __restrict__ acc_in,
                         u16* __restrict__ w5,
                         float* __restrict__ ebias, float* __restrict__ phys_out) {
    int bid = blockIdx.x;
    int t = threadIdx.x;
    if (bid < W5_BLKS) {
        int i = bid * 256 + t;               // 294912 total
        int e    = i & 7;
        int lane = (i >> 3) & 63;
        int g    = (i >> 9) & 7;
        int s    = i >> 12;                  // 0..71
        int o    = g * 32 + (lane & 31);
        int hi   = lane >> 5;
        int c    = (s & 7) * 16 + hi * 8 + e;
        int k    = s >> 3;
        w5[i] = f2bf(w[((size_t)o * C_IN + c) * KS + k]);
        return;
    }
    __shared__ float red[256];
    int o = bid - W5_BLKS;
    float sum = 0.f;
    for (int i = t; i < KTOT; i += 256) {
        int k = i % KS;                    // offset layout [c][k]
        float tk = k * 0.01f;              // DT
        float off = vel[i] * tk + 0.5f * acc_in[i] * tk * tk;
        sum += off * w[(size_t)o * KTOT + i];
    }
    red[t] = sum;
    __syncthreads();
    for (int h = 128; h > 0; h >>= 1) {
        if (t < h) red[t] += red[t + h];
        __syncthreads();
    }
    if (t == 0) ebias[o] = bias[o] + red[0];

    if (o == 0) {                          // phys
        __syncthreads();
        float pv = 0.f;
        for (int i = t; i < KTOT; i += 256) {
            float v = vel[i], a = acc_in[i];
            pv += v * v + a * a;
        }
        red[t] = pv;
        __syncthreads();
        for (int h = 128; h > 0; h >>= 1) {
            if (t < h) red[t] += red[t + h];
            __syncthreads();
        }
        if (t == 0) *phys_out = 0.01f * (red[0] / (float)KTOT);
    }
}

// ---------------------------------------------------------------------------
// Main: R11 fat-wave barrier-free K-loop (best: 41.7us) + FUSED x-transpose.
// The separate prep_xt kernel (33.5MB read + 16.8MB xt write, then 17.8MB
// re-read here) is replaced by an in-prologue transpose+cast+swizzle:
//  phase 1: thread t owns row r=t (l = clamp(lbase+r-4)); for each of 16
//    channel-16B-blocks: 8 coalesced-over-lanes f32 loads -> bf16 pack ->
//    ds_write at slot (cb ^ (r&15))  [same swizzle formula the read uses].
//  phase 2: rows 128..135 (halo): r = 128+(t&7), cb = t>>3, one unit each.
// Read path (LOAD_B) byte-identical to R11. Saves ~35MB HBM + one launch.
// Wave tile 128o x 128l (acc 256 regs, 1 wave/SIMD). Block = 2 waves.
// A: global->reg from L2-resident w5, register dbuf distance 1; no mid-loop
// barriers; compiler's counted vmcnt/lgkmcnt before first use.
// ---------------------------------------------------------------------------
__global__ __launch_bounds__(128, 1) void conv_main(const float* __restrict__ x,
                                                    const u16* __restrict__ w5,
                                                    const float* __restrict__ ebias,
                                                    float* __restrict__ out) {
    __shared__ u16 ldsx[17408];            // B tile: 136 rows x 256B = 34816 B

    int b     = blockIdx.y;
    int lbase = blockIdx.x * 128;
    int t     = threadIdx.x;               // 0..127
    int lane  = t & 63;
    int wm    = t >> 6;                    // wave = o-half (128 o each)
    int l31   = lane & 31;
    int hi    = lane >> 5;

    // A source: wave wm's 4 o-groups (g = wm*4+mi) -> contiguous 4KB/step
    const u16* alane = w5 + ((size_t)(wm * 4) * 64 + lane) * 8;

    #define LOAD_A(S, AF)                                                        \
        {                                                                        \
            const u16* p_ = alane + (size_t)(S) * 4096;                          \
            _Pragma("unroll")                                                    \
            for (int mi = 0; mi < 4; ++mi)                                       \
                AF[mi] = *reinterpret_cast<const bf16x8*>(p_ + mi * 512);        \
        }
    #define LOAD_B(S, BF)                                                        \
        {                                                                        \
            int k_ = (S) >> 3;                                                   \
            int sl_ = ((S) & 7) * 2 + hi;                                        \
            _Pragma("unroll")                                                    \
            for (int nj = 0; nj < 4; ++nj) {                                     \
                int row_  = nj * 32 + l31 + k_;                                  \
                int addr_ = row_ * 256 + ((sl_ ^ (row_ & 15)) << 4);             \
                BF[nj] = *reinterpret_cast<const bf16x8*>(ldsbase + addr_);      \
            }                                                                    \
        }
    #define MFMA16(AF, BF)                                                       \
        {                                                                        \
            _Pragma("unroll")                                                    \
            for (int mi = 0; mi < 4; ++mi)                                       \
                _Pragma("unroll")                                                \
                for (int nj = 0; nj < 4; ++nj)                                   \
                    acc[mi][nj] = __builtin_amdgcn_mfma_f32_32x32x16_bf16(       \
                        AF[mi], BF[nj], acc[mi][nj], 0, 0, 0);                   \
        }

    bf16x8 aA[4], aB[4], bA[4], bB[4];
    LOAD_A(0, aA);                         // issue A(0) first (L2 latency hidden
                                           // under the transpose below)

    // ---- fused B-tile transpose+cast+swizzle (replaces prep_xt + g2l16) ----
    const float* xb = x + (size_t)b * C_IN * LEN;
    {
        // phase 1: rows 0..127, one row per thread; lanes = consecutive l
        int r = t;
        int l = lbase + r - PAD;
        l = l < 0 ? 0 : (l > LEN - 1 ? LEN - 1 : l);
        int key = r & 15;
        float v[16][8];
        #pragma unroll
        for (int cb = 0; cb < 16; ++cb)
            #pragma unroll
            for (int e = 0; e < 8; ++e)
                v[cb][e] = xb[(size_t)(cb * 8 + e) * LEN + l];   // coalesced
        #pragma unroll
        for (int cb = 0; cb < 16; ++cb) {
            ushort8 u;
            #pragma unroll
            for (int e = 0; e < 8; ++e) u[e] = f2bf(v[cb][e]);
            *reinterpret_cast<ushort8*>(ldsx + r * 128 + ((cb ^ key) * 8)) = u;
        }
    }
    {
        // phase 2: halo rows 128..135, (row, cblk) unit per thread
        int r  = 128 + (t & 7);
        int cb = t >> 3;                   // 0..15
        int l = lbase + r - PAD;
        l = l < 0 ? 0 : (l > LEN - 1 ? LEN - 1 : l);
        ushort8 u;
        #pragma unroll
        for (int e = 0; e < 8; ++e)
            u[e] = f2bf(xb[(size_t)(cb * 8 + e) * LEN + l]);
        *reinterpret_cast<ushort8*>(ldsx + r * 128 + ((cb ^ (r & 15)) * 8)) = u;
    }
    __syncthreads();                       // B-tile ready; the only barrier

    f32x16 acc[4][4] = {};
    const char* ldsbase = reinterpret_cast<const char*>(ldsx);
    LOAD_B(0, bA);

    #pragma unroll
    for (int s = 0; s < NSTEP; s += 2) {
        LOAD_A(s + 1, aB);
        LOAD_B(s + 1, bB);
        MFMA16(aA, bA);
        if (s + 2 < NSTEP) { LOAD_A(s + 2, aA); LOAD_B(s + 2, bA); }
        MFMA16(aB, bB);
    }

    // ---- epilogue: 32x32 D layout col = lane&31 (l), row = (reg&3)+8*(reg>>2)+4*hi
    #pragma unroll
    for (int mi = 0; mi < 4; ++mi) {
        int o0 = wm * 128 + mi * 32 + hi * 4;
        #pragma unroll
        for (int nj = 0; nj < 4; ++nj) {
            int l = lbase + nj * 32 + l31;
            #pragma unroll
            for (int q = 0; q < 4; ++q) {
                f32x4 eb = *reinterpret_cast<const f32x4*>(ebias + o0 + q * 8);
                float* op = out + (size_t)(b * C_OUT + o0 + q * 8) * LEN + l;
                #pragma unroll
                for (int p = 0; p < 4; ++p)
                    op[(size_t)p * LEN] = acc[mi][nj][q * 4 + p] + eb[p];
            }
        }
    }
    #undef LOAD_A
    #undef LOAD_B
    #undef MFMA16
}

extern "C" void kernel_launch(void* const* d_in, const int* in_sizes, int n_in,
                              void* d_out, int out_size, void* d_ws, size_t ws_size,
                              hipStream_t stream) {
    const float* x      = (const float*)d_in[0];
    const float* weight = (const float*)d_in[1];
    const float* bias   = (const float*)d_in[2];
    const float* vel    = (const float*)d_in[3];
    const float* acc    = (const float*)d_in[4];
    float* out = (float*)d_out;

    char* ws = (char*)d_ws;
    u16*  w5    = (u16*)ws;                                   // 589,824 B
    float* ebias = (float*)(ws + (size_t)C_OUT * KTOT * 2);

    hipLaunchKernelGGL(prep_all, dim3(W5_BLKS + EB_BLKS), dim3(256), 0, stream,
                       weight, bias, vel, acc, w5, ebias,
                       out + (size_t)BATCH * C_OUT * LEN);
    hipLaunchKernelGGL(conv_main, dim3(LEN / 128, BATCH), dim3(128), 0, stream,
                       x, w5, ebias, out);
}